// Round 9
// baseline (510.377 us; speedup 1.0000x reference)
//
#include <hip/hip_runtime.h>
#include <hip/hip_cooperative_groups.h>
#include <math.h>

namespace cg = cooperative_groups;

// Problem constants: B=8, N=2048, D=512, S=4096
#define BATCH 8
#define NNODES 2048
#define DDIM 512
#define SWAPS 4096
#define M_TOTAL (BATCH * SWAPS)   // 32768
#define KD DDIM                   // 512 (dense GEMM K)
#define K2 DDIM                   // 512
#define N2 (DDIM / 2)             // 256

typedef __attribute__((ext_vector_type(8))) __bf16 bf16x8;   // MFMA A/B frag
typedef __attribute__((ext_vector_type(4))) float f32x4;      // MFMA C/D frag
typedef __attribute__((ext_vector_type(8))) unsigned short us8;
typedef unsigned short ushort_t;

// tanh-approx GELU (max |err| vs exact erf-GELU ~5e-4)
__device__ __forceinline__ float gelu_fast(float x) {
    const float u = 0.7978845608028654f * x * fmaf(0.044715f * x, x, 1.0f);
    const float e = __expf(-2.0f * fabsf(u));
    float t = (1.0f - e) / (1.0f + e);
    t = copysignf(t, u);
    return 0.5f * x * (1.0f + t);
}
__device__ __forceinline__ float softplus_f(float x) {
    return fmaxf(x, 0.0f) + log1pf(expf(-fabsf(x)));
}
__device__ __forceinline__ unsigned short f2bf(float f) {
    unsigned int u = __builtin_bit_cast(unsigned int, f);
    u += 0x7FFFu + ((u >> 16) & 1u);
    return (unsigned short)(u >> 16);
}
__device__ __forceinline__ float bf2f(unsigned short s) {
    return __builtin_bit_cast(float, (unsigned int)s << 16);
}
__device__ __forceinline__ void glds16(const void* g, void* l) {
    __builtin_amdgcn_global_load_lds(
        (const __attribute__((address_space(1))) void*)g,
        (__attribute__((address_space(3))) void*)l, 16, 0, 0);
}

// ---------------------------------------------------------------------------
// MEGA kernel: all three measured-best phase bodies (convert / R2-gemm1 /
// R4-fused-32swap) merged into ONE cooperative launch with 2 grid.sync()s.
// Rationale (R8 post-mortem): per-kernel arithmetic sums to ~90us but total
// is a schedule-invariant 166-171us across 7 rounds -> ~60-75us lives in
// inter-kernel launch/drain overhead.  This kills the 3-dispatch structure.
// Grid is dynamic (occupancy-derived, multiple of 8 so vb&7 XCD-affinity
// logic is preserved); every phase loop is grid-strided.
// Cross-phase coherence: __threadfence() (agent scope -> L2 wb/inv on
// gfx950 non-coherent per-XCD L2s) around each grid.sync(); P2->gather is
// additionally same-(vb&7)-class (same XCD L2) by construction.
// LDS: max(convert 9.2KB, gemm1 32KB, fused 32.5KB) = 33280B; at
// __launch_bounds__(256,4): 4 blocks/CU x 33280 = 133KB <= 160KB.
// ---------------------------------------------------------------------------
__global__ __launch_bounds__(256, 4) void mega(
    const float* __restrict__ h, const int* __restrict__ idx,
    const float* __restrict__ W1, const float* __restrict__ b1,
    const float* __restrict__ W2, const float* __restrict__ b2,
    const float* __restrict__ W3, const float* __restrict__ b3,
    float* __restrict__ out, ushort_t* __restrict__ P2,
    ushort_t* __restrict__ h_bf, ushort_t* __restrict__ W1pt,
    ushort_t* __restrict__ W2f)
{
    __shared__ __align__(16) char smem[33280];
    cg::grid_group gg = cg::this_grid();
    const int tid = threadIdx.x;

    // ================= Phase A: convert (4480 virtual blocks) =================
    for (int vb = blockIdx.x; vb < 4480; vb += gridDim.x) {
        if (vb < 4096) {                       // h: 8M elems, 8/thread
            const size_t i = ((size_t)vb * 256 + tid) * 8;
            float4 v0 = *(const float4*)(h + i);
            float4 v1 = *(const float4*)(h + i + 4);
            us8 o;
            o[0] = f2bf(v0.x); o[1] = f2bf(v0.y); o[2] = f2bf(v0.z); o[3] = f2bf(v0.w);
            o[4] = f2bf(v1.x); o[5] = f2bf(v1.y); o[6] = f2bf(v1.z); o[7] = f2bf(v1.w);
            *(us8*)(h_bf + i) = o;
        } else if (vb < 4096 + 256) {          // W1 transpose: 64k x 64n tiles
            ushort_t (*sT)[72] = (ushort_t(*)[72])smem;   // [64][72]
            const int tb = vb - 4096;
            const int kt = tb >> 3, nt = tb & 7;
            const int kl = tid >> 4;
            const int n4 = (tid & 15) * 4;
            #pragma unroll
            for (int p = 0; p < 4; ++p) {
                const int k_local = p * 16 + kl;
                float4 v = *(const float4*)(W1 + (size_t)(kt * 64 + k_local) * 512
                                            + nt * 64 + n4);
                sT[n4 + 0][k_local] = f2bf(v.x);
                sT[n4 + 1][k_local] = f2bf(v.y);
                sT[n4 + 2][k_local] = f2bf(v.z);
                sT[n4 + 3][k_local] = f2bf(v.w);
            }
            __syncthreads();
            const int n_local = tid >> 2, ch = tid & 3;
            const int j = (kt >> 3) * 512 + nt * 64 + n_local;
            const int d0 = (kt & 7) * 64 + ch * 16;
            us8 o0, o1;
            #pragma unroll
            for (int e = 0; e < 8; ++e) { o0[e] = sT[n_local][ch * 16 + e];
                                          o1[e] = sT[n_local][ch * 16 + 8 + e]; }
            *(us8*)(W1pt + (size_t)j * KD + d0)     = o0;
            *(us8*)(W1pt + (size_t)j * KD + d0 + 8) = o1;
            __syncthreads();                   // sT reuse across vb iterations
        } else {                               // W2: 131072 elems (512 x 256)
            size_t e = ((size_t)(vb - 4352) * 256 + tid) * 4;
            const int k = (int)(e >> 8), n = (int)(e & 255);
            const int kc = k >> 5, quad = (k >> 3) & 3, pos = k & 7;
            const size_t base = (size_t)kc * 8192 + quad * 8 + pos;
            float4 v = *(const float4*)(W2 + e);
            W2f[base + (size_t)(n + 0) * 32] = f2bf(v.x);
            W2f[base + (size_t)(n + 1) * 32] = f2bf(v.y);
            W2f[base + (size_t)(n + 2) * 32] = f2bf(v.z);
            W2f[base + (size_t)(n + 3) * 32] = f2bf(v.w);
        }
    }

    __threadfence();     // release: wb L2 so other XCDs see h_bf/W1pt/W2f
    gg.sync();
    __threadfence();     // acquire: invalidate local L2

    // ================= Phase B: gemm1 (2048 virtual blocks, R2-exact) ========
    {
        const int w = tid >> 6, lane = tid & 63;
        const int quad = lane >> 4, l16 = lane & 15;
        const int wr = w >> 1, wc = w & 1;
        const int row0 = tid >> 2, sub = tid & 3;
        const int cgk = (sub - (row0 >> 1)) & 3;

        for (int vb = blockIdx.x; vb < 2048; vb += gridDim.x) {
            const int xcd = vb & 7;            // == batch
            const int r = vb >> 3;
            const int m0 = xcd * NNODES + (r & 15) * 128;
            const int n0 = (r >> 4) * 128;

            const ushort_t* bA0 = h_bf + (size_t)(m0 + row0) * KD + cgk * 8;
            const ushort_t* bA1 = h_bf + (size_t)(m0 + row0 + 64) * KD + cgk * 8;
            const ushort_t* bB0 = W1pt + (size_t)(n0 + row0) * KD + cgk * 8;
            const ushort_t* bB1 = W1pt + (size_t)(n0 + row0 + 64) * KD + cgk * 8;

            int pa[4], pb[4];
            #pragma unroll
            for (int i = 0; i < 4; ++i) {
                const int rA = wr * 64 + i * 16 + l16;
                const int rB = wc * 64 + i * 16 + l16;
                pa[i] = rA * 64 + (((quad + (rA >> 1)) & 3) * 16);
                pb[i] = 8192 + rB * 64 + (((quad + (rB >> 1)) & 3) * 16);
            }

            f32x4 acc[4][4] = {};

            auto stage = [&](int kt, int half) {
                const int oo = kt * 32;
                char* base = smem + half * 16384;
                glds16(bA0 + oo, base + w * 1024);
                glds16(bA1 + oo, base + 4096 + w * 1024);
                glds16(bB0 + oo, base + 8192 + w * 1024);
                glds16(bB1 + oo, base + 12288 + w * 1024);
            };
            auto compute = [&](int half) {
                const char* base = smem + half * 16384;
                bf16x8 af[4], bfr[4];
                #pragma unroll
                for (int i = 0; i < 4; ++i) {
                    af[i]  = *(const bf16x8*)(base + pa[i]);
                    bfr[i] = *(const bf16x8*)(base + pb[i]);
                }
                #pragma unroll
                for (int i = 0; i < 4; ++i)
                    #pragma unroll
                    for (int jj = 0; jj < 4; ++jj)
                        acc[i][jj] = __builtin_amdgcn_mfma_f32_16x16x32_bf16(
                            af[i], bfr[jj], acc[i][jj], 0, 0, 0);
            };

            for (int kt = 0; kt < 16; kt += 2) {
                stage(kt, 0);
                stage(kt + 1, 1);
                __syncthreads();
                compute(0);
                compute(1);
                __syncthreads();
            }

            // epilogue: write P2[(b*2+nc)][node][sg*256+pos]
            #pragma unroll
            for (int jj = 0; jj < 4; ++jj) {
                const int j = n0 + wc * 64 + jj * 16 + l16;
                const int sg = j >> 9, nh = j & 511;
                const size_t base = ((size_t)(xcd * 2 + (nh >> 8)) * NNODES) * 1024
                                  + (size_t)(sg << 8) + (nh & 255);
                #pragma unroll
                for (int i = 0; i < 4; ++i) {
                    f32x4 v = acc[i][jj];
                    #pragma unroll
                    for (int rr = 0; rr < 4; ++rr) {
                        const int node = (m0 + wr * 64 + i * 16 + quad * 4 + rr) & (NNODES - 1);
                        P2[base + (size_t)node * 1024] = f2bf(v[rr]);
                    }
                }
            }
        }
    }

    __threadfence();
    gg.sync();
    __threadfence();

    // ================= Phase C: fused tail (1024 vblocks, R4-exact) ==========
    {
        const int w = tid >> 6, lane = tid & 63;
        const int quad = lane >> 4, l16 = lane & 15;

        for (int vb = blockIdx.x; vb < 1024; vb += gridDim.x) {
            const int b = vb & 7;                      // same XCD class as writer
            const int m0 = b * SWAPS + (vb >> 3) * 32; // 32 swaps per vblock

            // -------- gather x1 tile into LDS --------
            {
                const int row = tid >> 3;           // 0..31
                const int ws  = tid & 7;
                const int ap  = ws & 3;
                const int ncs = ws >> 2;
                const int acg = (ap - (row >> 1)) & 3;
                const int4 iv = *(const int4*)(idx + (size_t)(m0 + row) * 4);
                const ushort_t* Pr = P2 + (size_t)(b * 2 + ncs) * NNODES * 1024;
                const ushort_t* p0 = Pr + (size_t)iv.x * 1024 + 0 * 256;
                const ushort_t* p1 = Pr + (size_t)iv.y * 1024 + 1 * 256;
                const ushort_t* p2 = Pr + (size_t)iv.z * 1024 + 2 * 256;
                const ushort_t* p3 = Pr + (size_t)iv.w * 1024 + 3 * 256;
                #pragma unroll 4
                for (int it = 0; it < 8; ++it) {
                    const int kc = ncs * 8 + it;
                    const int pos0 = it * 32 + acg * 8;
                    us8 v0 = *(const us8*)(p0 + pos0);
                    us8 v1 = *(const us8*)(p1 + pos0);
                    us8 v2 = *(const us8*)(p2 + pos0);
                    us8 v3 = *(const us8*)(p3 + pos0);
                    const float* bp = b1 + ncs * 256 + pos0;
                    float4 ba = *(const float4*)bp;
                    float4 bb = *(const float4*)(bp + 4);
                    float s[8] = { ba.x, ba.y, ba.z, ba.w, bb.x, bb.y, bb.z, bb.w };
                    #pragma unroll
                    for (int e = 0; e < 8; ++e)
                        s[e] += bf2f(v0[e]) + bf2f(v1[e]) + bf2f(v2[e]) + bf2f(v3[e]);
                    us8 o;
                    #pragma unroll
                    for (int e = 0; e < 8; ++e) o[e] = f2bf(gelu_fast(s[e]));
                    *(us8*)(smem + kc * 2048 + row * 64 + ap * 16) = o;
                }
            }
            __syncthreads();

            // -------- barrier-free MFMA (GEMM2) --------
            const int cgw = w;                  // wave = 64-col group
            int paRow[2];
            #pragma unroll
            for (int i = 0; i < 2; ++i) {
                const int rA = i * 16 + l16;
                paRow[i] = rA * 64 + (((quad + (rA >> 1)) & 3) * 16);
            }
            const ushort_t* Bbase = W2f + (size_t)(cgw * 64 + l16) * 32 + quad * 8;

            f32x4 acc[2][4] = {};

            #pragma unroll 2
            for (int kc = 0; kc < 16; ++kc) {
                bf16x8 af0 = *(const bf16x8*)(smem + kc * 2048 + paRow[0]);
                bf16x8 af1 = *(const bf16x8*)(smem + kc * 2048 + paRow[1]);
                #pragma unroll
                for (int jf = 0; jf < 4; ++jf) {
                    bf16x8 bfr = *(const bf16x8*)(Bbase + (size_t)kc * 8192 + jf * 512);
                    acc[0][jf] = __builtin_amdgcn_mfma_f32_16x16x32_bf16(af0, bfr, acc[0][jf], 0, 0, 0);
                    acc[1][jf] = __builtin_amdgcn_mfma_f32_16x16x32_bf16(af1, bfr, acc[1][jf], 0, 0, 0);
                }
            }

            // -------- head dot --------
            float part[2][4] = {};
            #pragma unroll
            for (int jf = 0; jf < 4; ++jf) {
                const int n = cgw * 64 + jf * 16 + l16;
                const float w3 = W3[n];
                const float bb2 = b2[n];
                #pragma unroll
                for (int i = 0; i < 2; ++i) {
                    f32x4 v = acc[i][jf];
                    #pragma unroll
                    for (int rr = 0; rr < 4; ++rr)
                        part[i][rr] = fmaf(gelu_fast(v[rr] + bb2), w3, part[i][rr]);
                }
            }
            #pragma unroll
            for (int off = 1; off < 16; off <<= 1)
                #pragma unroll
                for (int i = 0; i < 2; ++i)
                    #pragma unroll
                    for (int rr = 0; rr < 4; ++rr)
                        part[i][rr] += __shfl_xor(part[i][rr], off);

            float* red = (float*)(smem + 32768);    // red[4][32]
            if (l16 == 0) {
                #pragma unroll
                for (int i = 0; i < 2; ++i)
                    #pragma unroll
                    for (int rr = 0; rr < 4; ++rr)
                        red[cgw * 32 + i * 16 + quad * 4 + rr] = part[i][rr];
            }
            __syncthreads();
            if (tid < 32) {
                const float v = red[tid] + red[32 + tid] + red[64 + tid] + red[96 + tid];
                out[m0 + tid] = softplus_f(v + b3[0]);
            }
            __syncthreads();                    // red reuse across vb iterations
        }
    }
}

// ---------------------------------------------------------------------------
// Workspace (peak 82.25 MB):
//   P2 @ 0 : 64 MB;  h_bf @ 64M : 16 MB;  W1pt @ 80M : 2 MB;  W2f @ 82M : 256KB
// ---------------------------------------------------------------------------
extern "C" void kernel_launch(void* const* d_in, const int* in_sizes, int n_in,
                              void* d_out, int out_size, void* d_ws, size_t ws_size,
                              hipStream_t stream) {
    const float* h   = (const float*)d_in[0];
    const int*   idx = (const int*)d_in[1];
    const float* W1  = (const float*)d_in[2];
    const float* b1  = (const float*)d_in[3];
    const float* W2  = (const float*)d_in[4];
    const float* b2  = (const float*)d_in[5];
    const float* W3  = (const float*)d_in[6];
    const float* b3  = (const float*)d_in[7];
    float* out = (float*)d_out;

    char* ws = (char*)d_ws;
    ushort_t* P2    = (ushort_t*)ws;
    ushort_t* h_bf  = (ushort_t*)(ws + (64u << 20));
    ushort_t* W1pt  = (ushort_t*)(ws + (80u << 20));
    ushort_t* W2f   = (ushort_t*)(ws + (82u << 20));

    // occupancy-derived cooperative grid (cached; host-only query, no sync)
    static int s_grid = 0;
    if (s_grid == 0) {
        int nb = 0;
        if (hipOccupancyMaxActiveBlocksPerMultiprocessor(&nb, mega, 256, 0)
                != hipSuccess || nb < 1)
            nb = 1;
        int g = nb * 256;            // 256 CUs on MI355X
        if (g > 1024) g = 1024;
        g &= ~7;                     // keep vb&7 XCD-affinity classes balanced
        if (g < 8) g = 8;
        s_grid = g;
    }

    void* args[] = { (void*)&h, (void*)&idx, (void*)&W1, (void*)&b1,
                     (void*)&W2, (void*)&b2, (void*)&W3, (void*)&b3,
                     (void*)&out, (void*)&P2, (void*)&h_bf, (void*)&W1pt,
                     (void*)&W2f };
    hipLaunchCooperativeKernel((const void*)mega, dim3(s_grid), dim3(256),
                               args, 0, stream);
}

// Round 10
// 172.180 us; speedup vs baseline: 2.9642x; 2.9642x over previous
//
#include <hip/hip_runtime.h>
#include <math.h>

// Problem constants: B=8, N=2048, D=512, S=4096
#define BATCH 8
#define NNODES 2048
#define DDIM 512
#define SWAPS 4096
#define M_TOTAL (BATCH * SWAPS)   // 32768
#define KD DDIM                   // 512 (dense GEMM K)
#define K2 DDIM                   // 512
#define N2 (DDIM / 2)             // 256

typedef __attribute__((ext_vector_type(8))) __bf16 bf16x8;   // MFMA A/B frag
typedef __attribute__((ext_vector_type(4))) float f32x4;      // MFMA C/D frag
typedef __attribute__((ext_vector_type(8))) unsigned short us8;
typedef unsigned short ushort_t;

// tanh-approx GELU (max |err| vs exact erf-GELU ~5e-4)
__device__ __forceinline__ float gelu_fast(float x) {
    const float u = 0.7978845608028654f * x * fmaf(0.044715f * x, x, 1.0f);
    const float e = __expf(-2.0f * fabsf(u));
    float t = (1.0f - e) / (1.0f + e);
    t = copysignf(t, u);
    return 0.5f * x * (1.0f + t);
}
__device__ __forceinline__ float softplus_f(float x) {
    return fmaxf(x, 0.0f) + log1pf(expf(-fabsf(x)));
}
__device__ __forceinline__ unsigned short f2bf(float f) {
    unsigned int u = __builtin_bit_cast(unsigned int, f);
    u += 0x7FFFu + ((u >> 16) & 1u);
    return (unsigned short)(u >> 16);
}
__device__ __forceinline__ float bf2f(unsigned short s) {
    return __builtin_bit_cast(float, (unsigned int)s << 16);
}
__device__ __forceinline__ void glds16(const void* g, void* l) {
    __builtin_amdgcn_global_load_lds(
        (const __attribute__((address_space(1))) void*)g,
        (__attribute__((address_space(3))) void*)l, 16, 0, 0);
}

// ---------------------------------------------------------------------------
// convert: h -> h_bf via us8 16B stores (4096 blocks);
// W1 -> W1pt[j][d] via LDS transpose -> CONTIGUOUS 16B global stores;
// W2 -> W2f fragment-major [kc*8192 + n*32 + quad*8 + pos].   (R2-exact)
// ---------------------------------------------------------------------------
__global__ __launch_bounds__(256) void convert_kernel(
    const float* __restrict__ h, const float* __restrict__ W1,
    const float* __restrict__ W2, ushort_t* __restrict__ h_bf,
    ushort_t* __restrict__ W1pt, ushort_t* __restrict__ W2f)
{
    const int bid = blockIdx.x;
    const int tid = threadIdx.x;
    if (bid < 4096) {                       // h: 8M elems, 8/thread
        const size_t i = ((size_t)bid * 256 + tid) * 8;
        float4 v0 = *(const float4*)(h + i);
        float4 v1 = *(const float4*)(h + i + 4);
        us8 o;
        o[0] = f2bf(v0.x); o[1] = f2bf(v0.y); o[2] = f2bf(v0.z); o[3] = f2bf(v0.w);
        o[4] = f2bf(v1.x); o[5] = f2bf(v1.y); o[6] = f2bf(v1.z); o[7] = f2bf(v1.w);
        *(us8*)(h_bf + i) = o;
    } else if (bid < 4096 + 256) {          // W1 transpose: 64k x 64n tiles
        __shared__ ushort_t sT[64][72];     // [n_local][k_local+pad]
        const int tb = bid - 4096;
        const int kt = tb >> 3, nt = tb & 7;     // 32 k-tiles, 8 n-tiles
        const int kl = tid >> 4;                 // 0..15 (per pass)
        const int n4 = (tid & 15) * 4;
        #pragma unroll
        for (int p = 0; p < 4; ++p) {
            const int k_local = p * 16 + kl;
            float4 v = *(const float4*)(W1 + (size_t)(kt * 64 + k_local) * 512
                                        + nt * 64 + n4);
            sT[n4 + 0][k_local] = f2bf(v.x);
            sT[n4 + 1][k_local] = f2bf(v.y);
            sT[n4 + 2][k_local] = f2bf(v.z);
            sT[n4 + 3][k_local] = f2bf(v.w);
        }
        __syncthreads();
        const int n_local = tid >> 2, ch = tid & 3;
        const int j = (kt >> 3) * 512 + nt * 64 + n_local;
        const int d0 = (kt & 7) * 64 + ch * 16;
        us8 o0, o1;
        #pragma unroll
        for (int e = 0; e < 8; ++e) { o0[e] = sT[n_local][ch * 16 + e];
                                      o1[e] = sT[n_local][ch * 16 + 8 + e]; }
        *(us8*)(W1pt + (size_t)j * KD + d0)     = o0;
        *(us8*)(W1pt + (size_t)j * KD + d0 + 8) = o1;
    } else {                                // W2: 131072 elems (512 x 256)
        size_t e = ((size_t)(bid - 4352) * 256 + tid) * 4;
        const int k = (int)(e >> 8), n = (int)(e & 255);
        const int kc = k >> 5, quad = (k >> 3) & 3, pos = k & 7;
        const size_t base = (size_t)kc * 8192 + quad * 8 + pos;
        float4 v = *(const float4*)(W2 + e);
        W2f[base + (size_t)(n + 0) * 32] = f2bf(v.x);
        W2f[base + (size_t)(n + 1) * 32] = f2bf(v.y);
        W2f[base + (size_t)(n + 2) * 32] = f2bf(v.z);
        W2f[base + (size_t)(n + 3) * 32] = f2bf(v.w);
    }
}

// ---------------------------------------------------------------------------
// Dense GEMM1 — R2-proven kernel body, EXCEPT: launched as TWO half-M
// dispatches (grid 1024 each, mtOff = 0 / 8).  Purpose (R10): each half
// ~23us vacates the top-5 profile slots so fused_tail and convert become
// measurable for the first time (both have been <45us bounds-only for 9
// rounds).  XCD affinity (bid&7 == batch) preserved in each half.
// ---------------------------------------------------------------------------
__global__ __launch_bounds__(256, 4) void gemm1_dense(
    const ushort_t* __restrict__ h_bf, const ushort_t* __restrict__ W1pt,
    ushort_t* __restrict__ P2, const int mtOff)
{
    __shared__ __align__(16) char smem[32768];

    const int tid = threadIdx.x;
    const int w = tid >> 6, lane = tid & 63;
    const int quad = lane >> 4, l16 = lane & 15;
    const int wr = w >> 1, wc = w & 1;

    const int bid = blockIdx.x;           // 1024 blocks per half
    const int xcd = bid & 7;              // == batch
    const int r = bid >> 3;               // 0..127
    const int m0 = xcd * NNODES + ((r & 7) + mtOff) * 128;
    const int n0 = (r >> 3) * 128;

    const int row0 = tid >> 2, sub = tid & 3;
    const int cg = (sub - (row0 >> 1)) & 3;
    const ushort_t* bA0 = h_bf + (size_t)(m0 + row0) * KD + cg * 8;
    const ushort_t* bA1 = h_bf + (size_t)(m0 + row0 + 64) * KD + cg * 8;
    const ushort_t* bB0 = W1pt + (size_t)(n0 + row0) * KD + cg * 8;
    const ushort_t* bB1 = W1pt + (size_t)(n0 + row0 + 64) * KD + cg * 8;

    int pa[4], pb[4];
    #pragma unroll
    for (int i = 0; i < 4; ++i) {
        const int rA = wr * 64 + i * 16 + l16;
        const int rB = wc * 64 + i * 16 + l16;
        pa[i] = rA * 64 + (((quad + (rA >> 1)) & 3) * 16);
        pb[i] = 8192 + rB * 64 + (((quad + (rB >> 1)) & 3) * 16);
    }

    f32x4 acc[4][4] = {};

    auto stage = [&](int kt, int half) {
        const int oo = kt * 32;
        char* base = smem + half * 16384;
        glds16(bA0 + oo, base + w * 1024);
        glds16(bA1 + oo, base + 4096 + w * 1024);
        glds16(bB0 + oo, base + 8192 + w * 1024);
        glds16(bB1 + oo, base + 12288 + w * 1024);
    };
    auto compute = [&](int half) {
        const char* base = smem + half * 16384;
        bf16x8 af[4], bfr[4];
        #pragma unroll
        for (int i = 0; i < 4; ++i) {
            af[i]  = *(const bf16x8*)(base + pa[i]);
            bfr[i] = *(const bf16x8*)(base + pb[i]);
        }
        #pragma unroll
        for (int i = 0; i < 4; ++i)
            #pragma unroll
            for (int jj = 0; jj < 4; ++jj)
                acc[i][jj] = __builtin_amdgcn_mfma_f32_16x16x32_bf16(
                    af[i], bfr[jj], acc[i][jj], 0, 0, 0);
    };

    for (int kt = 0; kt < 16; kt += 2) {
        stage(kt, 0);
        stage(kt + 1, 1);
        __syncthreads();
        compute(0);
        compute(1);
        __syncthreads();
    }

    // epilogue: write P2[(b*2+nc)][node][sg*256+pos]
    #pragma unroll
    for (int jj = 0; jj < 4; ++jj) {
        const int j = n0 + wc * 64 + jj * 16 + l16;
        const int sg = j >> 9, nh = j & 511;
        const size_t base = ((size_t)(xcd * 2 + (nh >> 8)) * NNODES) * 1024
                          + (size_t)(sg << 8) + (nh & 255);
        #pragma unroll
        for (int i = 0; i < 4; ++i) {
            f32x4 v = acc[i][jj];
            #pragma unroll
            for (int rr = 0; rr < 4; ++rr) {
                const int node = (m0 + wr * 64 + i * 16 + quad * 4 + rr) & (NNODES - 1);
                P2[base + (size_t)node * 1024] = f2bf(v[rr]);
            }
        }
    }
}

// ---------------------------------------------------------------------------
// FUSED gather + GEMM2 + head, two-phase/one-barrier (R2-measured version).
// ---------------------------------------------------------------------------
__global__ __launch_bounds__(512) void fused_tail(
    const ushort_t* __restrict__ P2, const int* __restrict__ idx,
    const float* __restrict__ b1, const ushort_t* __restrict__ W2f,
    const float* __restrict__ b2, const float* __restrict__ W3,
    const float* __restrict__ b3, float* __restrict__ out)
{
    __shared__ __align__(16) char smem[66560];   // A 64KB + red 1KB

    const int tid = threadIdx.x;
    const int w = tid >> 6, lane = tid & 63;
    const int quad = lane >> 4, l16 = lane & 15;

    const int bid = blockIdx.x;
    const int b = bid & 7;
    const int m0 = b * SWAPS + (bid >> 3) * 64;

    // ---------------- Phase 1: gather x1 tile into LDS ----------------
    {
        const int row = tid >> 3;           // 0..63
        const int ws  = tid & 7;
        const int ap  = ws & 3;             // physical 16B chunk
        const int ncs = ws >> 2;            // 0/1 (256-col half)
        const int acg = (ap - (row >> 1)) & 3;
        const int4 iv = *(const int4*)(idx + (size_t)(m0 + row) * 4);
        const ushort_t* Pr = P2 + (size_t)(b * 2 + ncs) * NNODES * 1024;
        const ushort_t* p0 = Pr + (size_t)iv.x * 1024 + 0 * 256;
        const ushort_t* p1 = Pr + (size_t)iv.y * 1024 + 1 * 256;
        const ushort_t* p2 = Pr + (size_t)iv.z * 1024 + 2 * 256;
        const ushort_t* p3 = Pr + (size_t)iv.w * 1024 + 3 * 256;
        #pragma unroll 4
        for (int it = 0; it < 8; ++it) {
            const int kc = ncs * 8 + it;
            const int pos0 = it * 32 + acg * 8;
            us8 v0 = *(const us8*)(p0 + pos0);
            us8 v1 = *(const us8*)(p1 + pos0);
            us8 v2 = *(const us8*)(p2 + pos0);
            us8 v3 = *(const us8*)(p3 + pos0);
            const float* bp = b1 + ncs * 256 + pos0;
            float4 ba = *(const float4*)bp;
            float4 bb = *(const float4*)(bp + 4);
            float s[8] = { ba.x, ba.y, ba.z, ba.w, bb.x, bb.y, bb.z, bb.w };
            #pragma unroll
            for (int e = 0; e < 8; ++e)
                s[e] += bf2f(v0[e]) + bf2f(v1[e]) + bf2f(v2[e]) + bf2f(v3[e]);
            us8 o;
            #pragma unroll
            for (int e = 0; e < 8; ++e) o[e] = f2bf(gelu_fast(s[e]));
            *(us8*)(smem + kc * 4096 + row * 64 + ap * 16) = o;
        }
    }
    __syncthreads();

    // ---------------- Phase 2: barrier-free MFMA ----------------
    const int rg = w >> 2, cg = w & 3;
    int paRow[2];
    #pragma unroll
    for (int i = 0; i < 2; ++i) {
        const int rA = rg * 32 + i * 16 + l16;
        paRow[i] = rA * 64 + (((quad + (rA >> 1)) & 3) * 16);
    }
    const ushort_t* Bbase = W2f + (size_t)(cg * 64 + l16) * 32 + quad * 8;

    f32x4 acc[2][4] = {};

    #pragma unroll 2
    for (int kc = 0; kc < 16; ++kc) {
        bf16x8 af0 = *(const bf16x8*)(smem + kc * 4096 + paRow[0]);
        bf16x8 af1 = *(const bf16x8*)(smem + kc * 4096 + paRow[1]);
        #pragma unroll
        for (int jf = 0; jf < 4; ++jf) {
            bf16x8 bfr = *(const bf16x8*)(Bbase + (size_t)kc * 8192 + jf * 512);
            acc[0][jf] = __builtin_amdgcn_mfma_f32_16x16x32_bf16(af0, bfr, acc[0][jf], 0, 0, 0);
            acc[1][jf] = __builtin_amdgcn_mfma_f32_16x16x32_bf16(af1, bfr, acc[1][jf], 0, 0, 0);
        }
    }

    // ---------------- epilogue: head dot ----------------
    float part[2][4] = {};
    #pragma unroll
    for (int jf = 0; jf < 4; ++jf) {
        const int n = cg * 64 + jf * 16 + l16;
        const float w3 = W3[n];
        const float bb2 = b2[n];
        #pragma unroll
        for (int i = 0; i < 2; ++i) {
            f32x4 v = acc[i][jf];
            #pragma unroll
            for (int rr = 0; rr < 4; ++rr)
                part[i][rr] = fmaf(gelu_fast(v[rr] + bb2), w3, part[i][rr]);
        }
    }
    #pragma unroll
    for (int off = 1; off < 16; off <<= 1)
        #pragma unroll
        for (int i = 0; i < 2; ++i)
            #pragma unroll
            for (int rr = 0; rr < 4; ++rr)
                part[i][rr] += __shfl_xor(part[i][rr], off);

    float* red = (float*)(smem + 65536);    // red[4][64]
    if (l16 == 0) {
        #pragma unroll
        for (int i = 0; i < 2; ++i)
            #pragma unroll
            for (int rr = 0; rr < 4; ++rr)
                red[cg * 64 + rg * 32 + i * 16 + quad * 4 + rr] = part[i][rr];
    }
    __syncthreads();
    if (tid < 64) {
        const float v = red[tid] + red[64 + tid] + red[128 + tid] + red[192 + tid];
        out[m0 + tid] = softplus_f(v + b3[0]);
    }
}

// ---------------------------------------------------------------------------
// Workspace (peak 82.25 MB):
//   P2 @ 0 : 64 MB;  h_bf @ 64M : 16 MB;  W1pt @ 80M : 2 MB;  W2f @ 82M : 256KB
// ---------------------------------------------------------------------------
extern "C" void kernel_launch(void* const* d_in, const int* in_sizes, int n_in,
                              void* d_out, int out_size, void* d_ws, size_t ws_size,
                              hipStream_t stream) {
    const float* h   = (const float*)d_in[0];
    const int*   idx = (const int*)d_in[1];
    const float* W1  = (const float*)d_in[2];
    const float* b1  = (const float*)d_in[3];
    const float* W2  = (const float*)d_in[4];
    const float* b2  = (const float*)d_in[5];
    const float* W3  = (const float*)d_in[6];
    const float* b3  = (const float*)d_in[7];
    float* out = (float*)d_out;

    char* ws = (char*)d_ws;
    ushort_t* P2    = (ushort_t*)ws;
    ushort_t* h_bf  = (ushort_t*)(ws + (64u << 20));
    ushort_t* W1pt  = (ushort_t*)(ws + (80u << 20));
    ushort_t* W2f   = (ushort_t*)(ws + (82u << 20));

    convert_kernel<<<4480, 256, 0, stream>>>(h, W1, W2, h_bf, W1pt, W2f);
    gemm1_dense<<<1024, 256, 0, stream>>>(h_bf, W1pt, P2, 0);
    gemm1_dense<<<1024, 256, 0, stream>>>(h_bf, W1pt, P2, 8);
    fused_tail<<<512, 512, 0, stream>>>(P2, idx, b1, W2f, b2, W3, b3, out);
}

// Round 11
// 169.573 us; speedup vs baseline: 3.0098x; 1.0154x over previous
//
#include <hip/hip_runtime.h>
#include <math.h>

// Problem constants: B=8, N=2048, D=512, S=4096
#define BATCH 8
#define NNODES 2048
#define DDIM 512
#define SWAPS 4096
#define M_TOTAL (BATCH * SWAPS)   // 32768
#define KD DDIM                   // 512 (dense GEMM K)
#define K2 DDIM                   // 512
#define N2 (DDIM / 2)             // 256

typedef __attribute__((ext_vector_type(8))) __bf16 bf16x8;   // MFMA A/B frag
typedef __attribute__((ext_vector_type(4))) float f32x4;      // MFMA C/D frag
typedef __attribute__((ext_vector_type(8))) unsigned short us8;
typedef unsigned short ushort_t;

// tanh-approx GELU (max |err| vs exact erf-GELU ~5e-4)
__device__ __forceinline__ float gelu_fast(float x) {
    const float u = 0.7978845608028654f * x * fmaf(0.044715f * x, x, 1.0f);
    const float e = __expf(-2.0f * fabsf(u));
    float t = (1.0f - e) / (1.0f + e);
    t = copysignf(t, u);
    return 0.5f * x * (1.0f + t);
}
__device__ __forceinline__ float softplus_f(float x) {
    return fmaxf(x, 0.0f) + log1pf(expf(-fabsf(x)));
}
__device__ __forceinline__ unsigned short f2bf(float f) {
    unsigned int u = __builtin_bit_cast(unsigned int, f);
    u += 0x7FFFu + ((u >> 16) & 1u);
    return (unsigned short)(u >> 16);
}
__device__ __forceinline__ float bf2f(unsigned short s) {
    return __builtin_bit_cast(float, (unsigned int)s << 16);
}
__device__ __forceinline__ void glds16(const void* g, void* l) {
    __builtin_amdgcn_global_load_lds(
        (const __attribute__((address_space(1))) void*)g,
        (__attribute__((address_space(3))) void*)l, 16, 0, 0);
}

// ---------------------------------------------------------------------------
// convert (R2-exact): h -> h_bf; W1 -> W1pt (LDS transpose); W2 -> W2f.
// ---------------------------------------------------------------------------
__global__ __launch_bounds__(256) void convert_kernel(
    const float* __restrict__ h, const float* __restrict__ W1,
    const float* __restrict__ W2, ushort_t* __restrict__ h_bf,
    ushort_t* __restrict__ W1pt, ushort_t* __restrict__ W2f)
{
    const int bid = blockIdx.x;
    const int tid = threadIdx.x;
    if (bid < 4096) {                       // h: 8M elems, 8/thread
        const size_t i = ((size_t)bid * 256 + tid) * 8;
        float4 v0 = *(const float4*)(h + i);
        float4 v1 = *(const float4*)(h + i + 4);
        us8 o;
        o[0] = f2bf(v0.x); o[1] = f2bf(v0.y); o[2] = f2bf(v0.z); o[3] = f2bf(v0.w);
        o[4] = f2bf(v1.x); o[5] = f2bf(v1.y); o[6] = f2bf(v1.z); o[7] = f2bf(v1.w);
        *(us8*)(h_bf + i) = o;
    } else if (bid < 4096 + 256) {          // W1 transpose: 64k x 64n tiles
        __shared__ ushort_t sT[64][72];     // [n_local][k_local+pad]
        const int tb = bid - 4096;
        const int kt = tb >> 3, nt = tb & 7;     // 32 k-tiles, 8 n-tiles
        const int kl = tid >> 4;                 // 0..15 (per pass)
        const int n4 = (tid & 15) * 4;
        #pragma unroll
        for (int p = 0; p < 4; ++p) {
            const int k_local = p * 16 + kl;
            float4 v = *(const float4*)(W1 + (size_t)(kt * 64 + k_local) * 512
                                        + nt * 64 + n4);
            sT[n4 + 0][k_local] = f2bf(v.x);
            sT[n4 + 1][k_local] = f2bf(v.y);
            sT[n4 + 2][k_local] = f2bf(v.z);
            sT[n4 + 3][k_local] = f2bf(v.w);
        }
        __syncthreads();
        const int n_local = tid >> 2, ch = tid & 3;
        const int j = (kt >> 3) * 512 + nt * 64 + n_local;
        const int d0 = (kt & 7) * 64 + ch * 16;
        us8 o0, o1;
        #pragma unroll
        for (int e = 0; e < 8; ++e) { o0[e] = sT[n_local][ch * 16 + e];
                                      o1[e] = sT[n_local][ch * 16 + 8 + e]; }
        *(us8*)(W1pt + (size_t)j * KD + d0)     = o0;
        *(us8*)(W1pt + (size_t)j * KD + d0 + 8) = o1;
    } else {                                // W2: 131072 elems (512 x 256)
        size_t e = ((size_t)(bid - 4352) * 256 + tid) * 4;
        const int k = (int)(e >> 8), n = (int)(e & 255);
        const int kc = k >> 5, quad = (k >> 3) & 3, pos = k & 7;
        const size_t base = (size_t)kc * 8192 + quad * 8 + pos;
        float4 v = *(const float4*)(W2 + e);
        W2f[base + (size_t)(n + 0) * 32] = f2bf(v.x);
        W2f[base + (size_t)(n + 1) * 32] = f2bf(v.y);
        W2f[base + (size_t)(n + 2) * 32] = f2bf(v.z);
        W2f[base + (size_t)(n + 3) * 32] = f2bf(v.w);
    }
}

// ---------------------------------------------------------------------------
// Dense GEMM1 (R2-exact, single 2048-block dispatch — R10 measured the
// two-way split costs +5.8us in launch overhead): 128x128 tile, 2-phase,
// launch_bounds(256,4) -> 4 blocks/CU.
// ---------------------------------------------------------------------------
__global__ __launch_bounds__(256, 4) void gemm1_dense(
    const ushort_t* __restrict__ h_bf, const ushort_t* __restrict__ W1pt,
    ushort_t* __restrict__ P2)
{
    __shared__ __align__(16) char smem[32768];

    const int tid = threadIdx.x;
    const int w = tid >> 6, lane = tid & 63;
    const int quad = lane >> 4, l16 = lane & 15;
    const int wr = w >> 1, wc = w & 1;

    const int bid = blockIdx.x;
    const int xcd = bid & 7;            // == batch
    const int r = bid >> 3;
    const int m0 = xcd * NNODES + (r & 15) * 128;
    const int n0 = (r >> 4) * 128;

    const int row0 = tid >> 2, sub = tid & 3;
    const int cg = (sub - (row0 >> 1)) & 3;
    const ushort_t* bA0 = h_bf + (size_t)(m0 + row0) * KD + cg * 8;
    const ushort_t* bA1 = h_bf + (size_t)(m0 + row0 + 64) * KD + cg * 8;
    const ushort_t* bB0 = W1pt + (size_t)(n0 + row0) * KD + cg * 8;
    const ushort_t* bB1 = W1pt + (size_t)(n0 + row0 + 64) * KD + cg * 8;

    int pa[4], pb[4];
    #pragma unroll
    for (int i = 0; i < 4; ++i) {
        const int rA = wr * 64 + i * 16 + l16;
        const int rB = wc * 64 + i * 16 + l16;
        pa[i] = rA * 64 + (((quad + (rA >> 1)) & 3) * 16);
        pb[i] = 8192 + rB * 64 + (((quad + (rB >> 1)) & 3) * 16);
    }

    f32x4 acc[4][4] = {};

    auto stage = [&](int kt, int half) {
        const int oo = kt * 32;
        char* base = smem + half * 16384;
        glds16(bA0 + oo, base + w * 1024);
        glds16(bA1 + oo, base + 4096 + w * 1024);
        glds16(bB0 + oo, base + 8192 + w * 1024);
        glds16(bB1 + oo, base + 12288 + w * 1024);
    };
    auto compute = [&](int half) {
        const char* base = smem + half * 16384;
        bf16x8 af[4], bfr[4];
        #pragma unroll
        for (int i = 0; i < 4; ++i) {
            af[i]  = *(const bf16x8*)(base + pa[i]);
            bfr[i] = *(const bf16x8*)(base + pb[i]);
        }
        #pragma unroll
        for (int i = 0; i < 4; ++i)
            #pragma unroll
            for (int jj = 0; jj < 4; ++jj)
                acc[i][jj] = __builtin_amdgcn_mfma_f32_16x16x32_bf16(
                    af[i], bfr[jj], acc[i][jj], 0, 0, 0);
    };

    for (int kt = 0; kt < 16; kt += 2) {
        stage(kt, 0);
        stage(kt + 1, 1);
        __syncthreads();
        compute(0);
        compute(1);
        __syncthreads();
    }

    // epilogue: write P2[(b*2+nc)][node][sg*256+pos]
    #pragma unroll
    for (int jj = 0; jj < 4; ++jj) {
        const int j = n0 + wc * 64 + jj * 16 + l16;
        const int sg = j >> 9, nh = j & 511;
        const size_t base = ((size_t)(xcd * 2 + (nh >> 8)) * NNODES) * 1024
                          + (size_t)(sg << 8) + (nh & 255);
        #pragma unroll
        for (int i = 0; i < 4; ++i) {
            f32x4 v = acc[i][jj];
            #pragma unroll
            for (int rr = 0; rr < 4; ++rr) {
                const int node = (m0 + wr * 64 + i * 16 + quad * 4 + rr) & (NNODES - 1);
                P2[base + (size_t)node * 1024] = f2bf(v[rr]);
            }
        }
    }
}

// ---------------------------------------------------------------------------
// FUSED gather + GEMM2 + head, v2: 2-tile persistent pipeline (T14).
// 256 blocks (1/CU) x 512 thr; each block owns TWO 64-swap tiles and two
// 64KB LDS A-buffers.  Tile-1's gather is chunk-pipelined (depth-2, named
// regs) against tile-0's MFMA: load chunk i+1 -> 2kc MFMA -> GELU+store
// chunk i.  All arithmetic / tile geometry / W2f traffic identical to the
// R2-measured version; only instruction ordering changes.
// LDS: buf0 @0 (64KB), buf1 @65536, red @131072 (1KB) = 132096B -> 1 blk/CU.
// ---------------------------------------------------------------------------
__global__ __launch_bounds__(512, 1) void fused_tail(
    const ushort_t* __restrict__ P2, const int* __restrict__ idx,
    const float* __restrict__ b1, const ushort_t* __restrict__ W2f,
    const float* __restrict__ b2, const float* __restrict__ W3,
    const float* __restrict__ b3, float* __restrict__ out)
{
    __shared__ __align__(16) char smem[132096];

    const int tid = threadIdx.x;
    const int w = tid >> 6, lane = tid & 63;
    const int quad = lane >> 4, l16 = lane & 15;

    const int bid = blockIdx.x;                   // 256 blocks
    const int b = bid & 7;                        // XCD == batch
    const int m0 = b * SWAPS + (bid >> 3) * 128;  // two 64-swap tiles

    // ---- gather thread mapping (identical to R2 version)
    const int grow = tid >> 3;            // 0..63
    const int gws  = tid & 7;
    const int ap   = gws & 3;             // physical 16B chunk
    const int ncs  = gws >> 2;            // 0/1 (256-col half)
    const int acg  = (ap - (grow >> 1)) & 3;
    const ushort_t* PrB = P2 + (size_t)(b * 2 + ncs) * NNODES * 1024;

    auto geluStore = [&](char* buf, int it, us8 v0, us8 v1, us8 v2, us8 v3) {
        const int kc = ncs * 8 + it;
        const int pos0 = it * 32 + acg * 8;
        const float* bp = b1 + ncs * 256 + pos0;
        float4 ba = *(const float4*)bp;
        float4 bb = *(const float4*)(bp + 4);
        float s[8] = { ba.x, ba.y, ba.z, ba.w, bb.x, bb.y, bb.z, bb.w };
        #pragma unroll
        for (int e = 0; e < 8; ++e)
            s[e] += bf2f(v0[e]) + bf2f(v1[e]) + bf2f(v2[e]) + bf2f(v3[e]);
        us8 o;
        #pragma unroll
        for (int e = 0; e < 8; ++e) o[e] = f2bf(gelu_fast(s[e]));
        *(us8*)(buf + kc * 4096 + grow * 64 + ap * 16) = o;
    };

    // ---- MFMA thread mapping
    const int rg = w >> 2, cgw = w & 3;
    int paRow[2];
    #pragma unroll
    for (int i = 0; i < 2; ++i) {
        const int rA = rg * 32 + i * 16 + l16;
        paRow[i] = rA * 64 + (((quad + (rA >> 1)) & 3) * 16);
    }
    const ushort_t* Bbase = W2f + (size_t)(cgw * 64 + l16) * 32 + quad * 8;

    // head epilogue: acc -> gelu -> W3 dot -> shfl -> red LDS -> out
    float* red = (float*)(smem + 131072);         // red[4][64]
    auto head = [&](f32x4 (&A)[2][4], int mt, bool preBar) {
        float part[2][4] = {};
        #pragma unroll
        for (int jf = 0; jf < 4; ++jf) {
            const int n = cgw * 64 + jf * 16 + l16;
            const float w3 = W3[n];
            const float bb2 = b2[n];
            #pragma unroll
            for (int i = 0; i < 2; ++i) {
                f32x4 v = A[i][jf];
                #pragma unroll
                for (int rr = 0; rr < 4; ++rr)
                    part[i][rr] = fmaf(gelu_fast(v[rr] + bb2), w3, part[i][rr]);
            }
        }
        #pragma unroll
        for (int off = 1; off < 16; off <<= 1)
            #pragma unroll
            for (int i = 0; i < 2; ++i)
                #pragma unroll
                for (int rr = 0; rr < 4; ++rr)
                    part[i][rr] += __shfl_xor(part[i][rr], off);
        if (preBar) __syncthreads();      // t0 red-readers done before t1 writes
        if (l16 == 0) {
            #pragma unroll
            for (int i = 0; i < 2; ++i)
                #pragma unroll
                for (int rr = 0; rr < 4; ++rr)
                    red[cgw * 64 + rg * 32 + i * 16 + quad * 4 + rr] = part[i][rr];
        }
        __syncthreads();
        if (tid < 64) {
            const float v = red[tid] + red[64 + tid] + red[128 + tid] + red[192 + tid];
            out[mt + tid] = softplus_f(v + b3[0]);
        }
    };

    char* buf0 = smem;
    char* buf1 = smem + 65536;

    // ================= tile 0 gather (serial prologue) =================
    {
        const int4 iv = *(const int4*)(idx + (size_t)(m0 + grow) * 4);
        const ushort_t* p0 = PrB + (size_t)iv.x * 1024 + 0 * 256;
        const ushort_t* p1 = PrB + (size_t)iv.y * 1024 + 1 * 256;
        const ushort_t* p2 = PrB + (size_t)iv.z * 1024 + 2 * 256;
        const ushort_t* p3 = PrB + (size_t)iv.w * 1024 + 3 * 256;
        #pragma unroll 4
        for (int it = 0; it < 8; ++it) {
            const int pos0 = it * 32 + acg * 8;
            us8 v0 = *(const us8*)(p0 + pos0);
            us8 v1 = *(const us8*)(p1 + pos0);
            us8 v2 = *(const us8*)(p2 + pos0);
            us8 v3 = *(const us8*)(p3 + pos0);
            geluStore(buf0, it, v0, v1, v2, v3);
        }
    }
    __syncthreads();

    // ============ tile-0 MFMA pipelined with tile-1 gather =============
    f32x4 acc0[2][4] = {};
    auto mfma2 = [&](const char* buf, int kc0, f32x4 (&A)[2][4]) {
        #pragma unroll
        for (int kc = kc0; kc < kc0 + 2; ++kc) {
            bf16x8 af0 = *(const bf16x8*)(buf + kc * 4096 + paRow[0]);
            bf16x8 af1 = *(const bf16x8*)(buf + kc * 4096 + paRow[1]);
            #pragma unroll
            for (int jf = 0; jf < 4; ++jf) {
                bf16x8 bfr = *(const bf16x8*)(Bbase + (size_t)kc * 8192 + jf * 512);
                A[0][jf] = __builtin_amdgcn_mfma_f32_16x16x32_bf16(af0, bfr, A[0][jf], 0, 0, 0);
                A[1][jf] = __builtin_amdgcn_mfma_f32_16x16x32_bf16(af1, bfr, A[1][jf], 0, 0, 0);
            }
        }
    };
    {
        const int4 iv = *(const int4*)(idx + (size_t)(m0 + 64 + grow) * 4);
        const ushort_t* q0 = PrB + (size_t)iv.x * 1024 + 0 * 256;
        const ushort_t* q1 = PrB + (size_t)iv.y * 1024 + 1 * 256;
        const ushort_t* q2 = PrB + (size_t)iv.z * 1024 + 2 * 256;
        const ushort_t* q3 = PrB + (size_t)iv.w * 1024 + 3 * 256;
        auto loadC = [&](int it, us8& v0, us8& v1, us8& v2, us8& v3) {
            const int pos0 = it * 32 + acg * 8;
            v0 = *(const us8*)(q0 + pos0);
            v1 = *(const us8*)(q1 + pos0);
            v2 = *(const us8*)(q2 + pos0);
            v3 = *(const us8*)(q3 + pos0);
        };
        us8 a0, a1, a2, a3, c0, c1, c2, c3;
        loadC(0, a0, a1, a2, a3);
        #pragma unroll
        for (int it = 0; it < 8; it += 2) {
            loadC(it + 1, c0, c1, c2, c3);       // issue next chunk early
            mfma2(buf0, it * 2, acc0);           // kc = 2it, 2it+1
            geluStore(buf1, it, a0, a1, a2, a3); // consume chunk it
            if (it + 2 < 8) loadC(it + 2, a0, a1, a2, a3);
            mfma2(buf0, it * 2 + 2, acc0);       // kc = 2it+2, 2it+3
            geluStore(buf1, it + 1, c0, c1, c2, c3);
        }
    }

    // tile-0 head (its internal __syncthreads also fences buf1 ds_writes)
    head(acc0, m0, false);

    // ================= tile 1 MFMA + head =================
    f32x4 acc1[2][4] = {};
    #pragma unroll 2
    for (int kc = 0; kc < 16; kc += 2) mfma2(buf1, kc, acc1);
    head(acc1, m0 + 64, true);
}

// ---------------------------------------------------------------------------
// Workspace (peak 82.25 MB):
//   P2 @ 0 : 64 MB;  h_bf @ 64M : 16 MB;  W1pt @ 80M : 2 MB;  W2f @ 82M : 256KB
// ---------------------------------------------------------------------------
extern "C" void kernel_launch(void* const* d_in, const int* in_sizes, int n_in,
                              void* d_out, int out_size, void* d_ws, size_t ws_size,
                              hipStream_t stream) {
    const float* h   = (const float*)d_in[0];
    const int*   idx = (const int*)d_in[1];
    const float* W1  = (const float*)d_in[2];
    const float* b1  = (const float*)d_in[3];
    const float* W2  = (const float*)d_in[4];
    const float* b2  = (const float*)d_in[5];
    const float* W3  = (const float*)d_in[6];
    const float* b3  = (const float*)d_in[7];
    float* out = (float*)d_out;

    char* ws = (char*)d_ws;
    ushort_t* P2    = (ushort_t*)ws;
    ushort_t* h_bf  = (ushort_t*)(ws + (64u << 20));
    ushort_t* W1pt  = (ushort_t*)(ws + (80u << 20));
    ushort_t* W2f   = (ushort_t*)(ws + (82u << 20));

    convert_kernel<<<4480, 256, 0, stream>>>(h, W1, W2, h_bf, W1pt, W2f);
    gemm1_dense<<<2048, 256, 0, stream>>>(h_bf, W1pt, P2);
    fused_tail<<<256, 512, 0, stream>>>(P2, idx, b1, W2f, b2, W3, b3, out);
}